// Round 6
// baseline (227.076 us; speedup 1.0000x reference)
//
#include <hip/hip_runtime.h>
#include <hip/hip_bf16.h>

typedef __attribute__((ext_vector_type(8))) short short8;
typedef __attribute__((ext_vector_type(4))) short short4v;
typedef __attribute__((ext_vector_type(4))) float floatx4;

union BF8 { short8 v; __hip_bfloat16 b[8]; };
union BF4U { ushort4 u; __hip_bfloat16 b[4]; };
union S4U { uint2 u; short4v v; };

__device__ __forceinline__ short8 load8(const __hip_bfloat16* p) {
    return *reinterpret_cast<const short8*>(p);
}
__device__ __forceinline__ short4v load4(const __hip_bfloat16* p) {
    return *reinterpret_cast<const short4v*>(p);
}

__device__ __forceinline__ void storeC(float* p, float v) { *p = v; }
__device__ __forceinline__ void storeC(__hip_bfloat16* p, float v) { *p = __float2bfloat16(v); }

// pack two fp32 -> two bf16 (round-half-up) in one dword: [lo]=a, [hi]=b
__device__ __forceinline__ unsigned pack_bf16(float a, float b) {
    unsigned ua = __float_as_uint(a) + 0x8000u;
    unsigned ub = __float_as_uint(b) + 0x8000u;
    return __builtin_amdgcn_perm(ub, ua, 0x07060302u);
}

// 2^x (v_exp_f32); scale/log2e pre-folded into Q
__device__ __forceinline__ float exp2_fast(float x) {
#if __has_builtin(__builtin_amdgcn_exp2f)
    return __builtin_amdgcn_exp2f(x);
#else
    return __expf(x * 0.6931471805599453f);
#endif
}

// 16x16x16 bf16 MFMA (K=16): A/B are 4 bf16 (2 VGPRs). The C-layout of a
// 16x16 S^T tile (lane: k=lq*4+r, q=lr) IS this shape's A-layout -> PV needs
// no cross-lane transform at all.
#if __has_builtin(__builtin_amdgcn_mfma_f32_16x16x16_bf16)
__device__ __forceinline__ floatx4 mfma16(short4v a, short4v b, floatx4 c) {
    return __builtin_amdgcn_mfma_f32_16x16x16_bf16(a, b, c, 0, 0, 0);
}
#elif __has_builtin(__builtin_amdgcn_mfma_f32_16x16x16bf16_1k)
__device__ __forceinline__ floatx4 mfma16(short4v a, short4v b, floatx4 c) {
    return __builtin_amdgcn_mfma_f32_16x16x16bf16_1k(a, b, c, 0, 0, 0);
}
#else
__device__ __forceinline__ floatx4 mfma16(short4v a, short4v b, floatx4 c) {
    asm volatile("v_mfma_f32_16x16x16_bf16 %0, %1, %2, %0"
                 : "+v"(c) : "v"(a), "v"(b));
    return c;
}
#endif

// async global->LDS, 16B per lane. LDS dest must be wave-uniform base + lane*16.
__device__ __forceinline__ void gload_lds16(const __hip_bfloat16* g, __hip_bfloat16* l) {
    __builtin_amdgcn_global_load_lds(
        (const __attribute__((address_space(1))) void*)g,
        (__attribute__((address_space(3))) void*)l, 16, 0, 0);
}

// -------- fp32 -> bf16 casts: y=0 hidden states (1M float4), y=1 the 4 weights ----
__global__ __launch_bounds__(256) void cast_all(const float* __restrict__ hs,
                                                const float* __restrict__ wq,
                                                const float* __restrict__ wk,
                                                const float* __restrict__ wv,
                                                const float* __restrict__ wo,
                                                __hip_bfloat16* __restrict__ Xb,
                                                __hip_bfloat16* __restrict__ Wb) {
    int i = blockIdx.x * 256 + threadIdx.x;
    const float* src;
    __hip_bfloat16* dst;
    if (blockIdx.y == 0) {
        src = hs; dst = Xb;
    } else {
        int m = i >> 18;
        src = (m == 0) ? wq : (m == 1) ? wk : (m == 2) ? wv : wo;
        src -= (size_t)m * 1048576;
        dst = Wb;
    }
    float4 v = reinterpret_cast<const float4*>(src)[i];
    BF4U u;
    u.b[0] = __float2bfloat16(v.x);
    u.b[1] = __float2bfloat16(v.y);
    u.b[2] = __float2bfloat16(v.z);
    u.b[3] = __float2bfloat16(v.w);
    reinterpret_cast<ushort4*>(dst)[i] = u.u;
}

// ---------------- GEMM: C[M,N] = A[M,K] * B^T  (B given as [N,K] row-major) --------
template <typename OutT>
__global__ __launch_bounds__(256) void gemm_bt(const __hip_bfloat16* __restrict__ A,
                                               const __hip_bfloat16* __restrict__ B0,
                                               OutT* __restrict__ C0,
                                               int N, int Kd,
                                               size_t zsB, size_t zsC,
                                               int normz, const float* __restrict__ scale_p) {
    __shared__ __hip_bfloat16 lA[128 * 32];
    __shared__ __hip_bfloat16 lB[128 * 32];
    const __hip_bfloat16* B = B0 + zsB * blockIdx.z;
    OutT* C = C0 + zsC * blockIdx.z;
    const int t = threadIdx.x;
    const int m0 = blockIdx.x * 128, n0 = blockIdx.y * 128;
    const int w = t >> 6, l = t & 63;
    const int wr = (w >> 1) * 64, wc = (w & 1) * 64;
    const int lr = l & 15, lq = l >> 4;

    const floatx4 zero4 = {0.f, 0.f, 0.f, 0.f};
    floatx4 acc[4][4];
#pragma unroll
    for (int mt = 0; mt < 4; ++mt)
#pragma unroll
        for (int nt = 0; nt < 4; ++nt) acc[mt][nt] = zero4;

    for (int k0 = 0; k0 < Kd; k0 += 32) {
#pragma unroll
        for (int i = 0; i < 2; ++i) {
            int flat = t + i * 256;
            int row = flat >> 2, ch = flat & 3;
            gload_lds16(A + (size_t)(m0 + row) * Kd + k0 + ch * 8, lA + flat * 8);
            gload_lds16(B + (size_t)(n0 + row) * Kd + k0 + ch * 8, lB + flat * 8);
        }
        __syncthreads();
        short8 af[4], bfr[4];
#pragma unroll
        for (int mt = 0; mt < 4; ++mt)
            af[mt] = load8(lA + (wr + mt * 16 + lr) * 32 + lq * 8);
#pragma unroll
        for (int nt = 0; nt < 4; ++nt)
            bfr[nt] = load8(lB + (wc + nt * 16 + lr) * 32 + lq * 8);
#pragma unroll
        for (int mt = 0; mt < 4; ++mt)
#pragma unroll
            for (int nt = 0; nt < 4; ++nt)
                acc[mt][nt] = __builtin_amdgcn_mfma_f32_16x16x32_bf16(
                    af[mt], bfr[nt], acc[mt][nt], 0, 0, 0);
        __syncthreads();
    }

    if (normz && blockIdx.z < 2) {
        const float fac = (blockIdx.z == 0) ? (*scale_p * 1.44269504f) : 1.0f;
#pragma unroll
        for (int mt = 0; mt < 4; ++mt)
#pragma unroll
            for (int r = 0; r < 4; ++r) {
                float ss = 0.f;
#pragma unroll
                for (int nt = 0; nt < 4; ++nt) {
                    float v = acc[mt][nt][r];
                    ss += v * v;
                }
                ss += __shfl_xor(ss, 1, 64);
                ss += __shfl_xor(ss, 2, 64);
                ss += __shfl_xor(ss, 4, 64);
                ss += __shfl_xor(ss, 8, 64);
                float inv = fac / (sqrtf(ss) + 1e-6f);
#pragma unroll
                for (int nt = 0; nt < 4; ++nt) acc[mt][nt][r] *= inv;
            }
    }

#pragma unroll
    for (int mt = 0; mt < 4; ++mt)
#pragma unroll
        for (int nt = 0; nt < 4; ++nt)
#pragma unroll
            for (int r = 0; r < 4; ++r) {
                int row = m0 + wr + mt * 16 + lq * 4 + r;
                int col = n0 + wc + nt * 16 + lr;
                storeC(C + (size_t)row * N + col, acc[mt][nt][r]);
            }
}

// ---------------- V [B,S,H,hd] -> Vt [B,H,hd,S] ----------------
__global__ __launch_bounds__(256) void transpose_v(const __hip_bfloat16* __restrict__ V,
                                                   __hip_bfloat16* __restrict__ Vt) {
    const int S = 2048, D = 1024;
    __shared__ __hip_bfloat16 tile[64][72];
    int t = threadIdx.x;
    int s0 = blockIdx.x * 64;
    int bh = blockIdx.y, b = bh >> 4, h = bh & 15;
    const __hip_bfloat16* src = V + ((size_t)b * S) * D + h * 64;
#pragma unroll
    for (int i = 0; i < 2; ++i) {
        int flat = t + i * 256;
        int sr = flat >> 3, ch = flat & 7;
        *reinterpret_cast<short8*>(&tile[sr][ch * 8]) =
            load8(src + (size_t)(s0 + sr) * D + ch * 8);
    }
    __syncthreads();
    __hip_bfloat16* dst = Vt + (size_t)bh * 64 * S;
#pragma unroll
    for (int i = 0; i < 2; ++i) {
        int flat = t + i * 256;
        int d = flat >> 3, sc = flat & 7;
        BF8 u;
#pragma unroll
        for (int j = 0; j < 8; ++j) u.b[j] = tile[sc * 8 + j][d];
        *reinterpret_cast<short8*>(dst + (size_t)d * S + s0 + sc * 8) = u.v;
    }
}

// ---------------- causal flash attention: paired q-tiles, no LDS in k-loop -------
// S^T = K.Q^T via 16x16x32; P exits in C-layout (lane: k=lq*4+r, q=lr) which IS
// the A-layout of the 16x16x16 MFMA -> PV = two K=16 MFMAs per tile, zero
// cross-lane movement. No prefetch (R5's spill lesson). Uniform 66 steps/block.
__global__ __launch_bounds__(256) void flash_attn(const __hip_bfloat16* __restrict__ Q,
                                                  const __hip_bfloat16* __restrict__ K,
                                                  const __hip_bfloat16* __restrict__ Vt,
                                                  __hip_bfloat16* __restrict__ O) {
    const int S = 2048, D = 1024;
    __shared__ __align__(16) char smem[20480];  // epilogue only: 4 x 64x20 fp32
    const int t = threadIdx.x;
    const int w = t >> 6, l = t & 63;
    const int lr = l & 15, lq = l >> 4;
    const int id = blockIdx.x;
    const int bh = (id & 7) * 4 + ((id >> 3) & 3);  // 4 heads per XCD (id%8 ~ XCD)
    const int pr = id >> 5;                          // 0..15 pair index
    const int b = bh >> 4, h = bh & 15;
    const __hip_bfloat16* Qb = Q + ((size_t)b * S) * D + h * 64;
    const __hip_bfloat16* Kb = K + ((size_t)b * S) * D + h * 64;
    const __hip_bfloat16* Vb = Vt + (size_t)bh * 64 * S;
    float* buf = reinterpret_cast<float*>(smem);

#pragma unroll 1
    for (int tile = 0; tile < 2; ++tile) {
        const int jq = (tile == 0) ? (31 - pr) : pr;
        const int q0 = jq * 64;

        short8 bq[4][2];
#pragma unroll
        for (int nt = 0; nt < 4; ++nt)
#pragma unroll
            for (int kt = 0; kt < 2; ++kt)
                bq[nt][kt] = load8(Qb + (size_t)(q0 + nt * 16 + lr) * D + kt * 32 + lq * 8);

        const floatx4 zero4 = {0.f, 0.f, 0.f, 0.f};
        floatx4 oacc[4][4];
        float lsum[4] = {0.f, 0.f, 0.f, 0.f};
#pragma unroll
        for (int mt = 0; mt < 4; ++mt)
#pragma unroll
            for (int nt = 0; nt < 4; ++nt) oacc[mt][nt] = zero4;

        const int klast = 2 * jq + 1;  // inclusive last 32-wide k-step
        const int kmask = 2 * jq;      // steps >= kmask need the causal mask

        if (w <= klast) {
#pragma unroll 1
            for (int ks = w; ks <= klast; ks += 4) {
                const int k0 = ks * 32;
                short8 bk[2][2];
#pragma unroll
                for (int mt = 0; mt < 2; ++mt)
#pragma unroll
                    for (int kt = 0; kt < 2; ++kt)
                        bk[mt][kt] = load8(Kb + (size_t)(k0 + mt * 16 + lr) * D + kt * 32 + lq * 8);
                // S^T = K.Q^T
                floatx4 sacc[2][4];
#pragma unroll
                for (int mt = 0; mt < 2; ++mt)
#pragma unroll
                    for (int nt = 0; nt < 4; ++nt) sacc[mt][nt] = zero4;
#pragma unroll
                for (int mt = 0; mt < 2; ++mt)
#pragma unroll
                    for (int nt = 0; nt < 4; ++nt)
#pragma unroll
                        for (int kt = 0; kt < 2; ++kt)
                            sacc[mt][nt] = __builtin_amdgcn_mfma_f32_16x16x32_bf16(
                                bk[mt][kt], bq[nt][kt], sacc[mt][nt], 0, 0, 0);
                // V B-fragments for the two K=16 PV MFMAs: lane needs
                // V[k0+mt*16+lq*4+i][ntd*16+lr] -> 8B row-chunks of Vt.
                short4v bv[2][4];
#pragma unroll
                for (int mt = 0; mt < 2; ++mt)
#pragma unroll
                    for (int ntd = 0; ntd < 4; ++ntd)
                        bv[mt][ntd] = load4(Vb + (size_t)(ntd * 16 + lr) * S + k0 + mt * 16 + lq * 4);
                const bool domask = ks >= kmask;  // wave-uniform
                short4v ap[2][4];
#pragma unroll
                for (int mt = 0; mt < 2; ++mt)
#pragma unroll
                    for (int nt = 0; nt < 4; ++nt) {
                        float p0 = exp2_fast(sacc[mt][nt][0]);
                        float p1 = exp2_fast(sacc[mt][nt][1]);
                        float p2 = exp2_fast(sacc[mt][nt][2]);
                        float p3 = exp2_fast(sacc[mt][nt][3]);
                        if (domask) {
                            const int qg = q0 + nt * 16 + lr;
                            const int kb = k0 + mt * 16 + lq * 4;
                            p0 = (kb + 0 <= qg) ? p0 : 0.f;
                            p1 = (kb + 1 <= qg) ? p1 : 0.f;
                            p2 = (kb + 2 <= qg) ? p2 : 0.f;
                            p3 = (kb + 3 <= qg) ? p3 : 0.f;
                        }
                        lsum[nt] += (p0 + p1) + (p2 + p3);
                        S4U u;
                        u.u.x = pack_bf16(p0, p1);
                        u.u.y = pack_bf16(p2, p3);
                        ap[mt][nt] = u.v;
                    }
                // PV: oacc[q-tile][d-tile] += P(K=16) . V(K=16), mt = k-subtile
#pragma unroll
                for (int mt = 0; mt < 2; ++mt)
#pragma unroll
                    for (int ntq = 0; ntq < 4; ++ntq)
#pragma unroll
                        for (int ntd = 0; ntd < 4; ++ntd)
                            oacc[ntq][ntd] = mfma16(ap[mt][ntq], bv[mt][ntd], oacc[ntq][ntd]);
            }
        }

        // reduce lsum over the 4 lq-quads (q index = nt*16+lr is lr-indexed)
#pragma unroll
        for (int nt = 0; nt < 4; ++nt) {
            float s = lsum[nt];
            s += __shfl_xor(s, 16, 64);
            s += __shfl_xor(s, 32, 64);
            lsum[nt] = s;
        }

        // ---- cross-wave reduce: d in 4 chunks of 16, buf[w][64][20] fp32 ----
        const int row = t >> 2, c0 = (t & 3) * 4;
        __hip_bfloat16* Ob = O + ((size_t)b * S) * D + h * 64;
        float inv = 0.f;
        __syncthreads();  // previous tile's epilogue reads done before overwrite
#pragma unroll 1
        for (int chunk = 0; chunk < 4; ++chunk) {
#pragma unroll
            for (int mtq = 0; mtq < 4; ++mtq)
#pragma unroll
                for (int r = 0; r < 4; ++r)
                    buf[w * 1280 + (mtq * 16 + lq * 4 + r) * 20 + lr] = oacc[mtq][chunk][r];
            if (chunk == 0 && lq == 0) {
#pragma unroll
                for (int nt = 0; nt < 4; ++nt)
                    buf[w * 1280 + (nt * 16 + lr) * 20 + 16] = lsum[nt];
            }
            __syncthreads();
            if (chunk == 0) {
                float Lt = buf[row * 20 + 16] + buf[1280 + row * 20 + 16] +
                           buf[2560 + row * 20 + 16] + buf[3840 + row * 20 + 16];
                inv = 1.f / Lt;
            }
            float4 a = {0.f, 0.f, 0.f, 0.f};
#pragma unroll
            for (int w2 = 0; w2 < 4; ++w2) {
                float4 v = *reinterpret_cast<const float4*>(buf + w2 * 1280 + row * 20 + c0);
                a.x += v.x; a.y += v.y; a.z += v.z; a.w += v.w;
            }
            uint2 d;
            d.x = pack_bf16(a.x * inv, a.y * inv);
            d.y = pack_bf16(a.z * inv, a.w * inv);
            *reinterpret_cast<uint2*>(Ob + (size_t)(q0 + row) * D + chunk * 16 + c0) = d;
            if (chunk < 3) __syncthreads();  // WAR before next chunk's writes
        }
    }
}

extern "C" void kernel_launch(void* const* d_in, const int* in_sizes, int n_in,
                              void* d_out, int out_size, void* d_ws, size_t ws_size,
                              hipStream_t stream) {
    const float* hs  = (const float*)d_in[0];  // [2,2048,1024]
    const float* wq  = (const float*)d_in[1];  // [1024,1024]
    const float* wk  = (const float*)d_in[2];
    const float* wv  = (const float*)d_in[3];
    const float* wo  = (const float*)d_in[4];
    const float* qkf = (const float*)d_in[5];  // scalar

    char* ws = (char*)d_ws;
    const size_t MB = 1024 * 1024;
    __hip_bfloat16* Xb  = (__hip_bfloat16*)(ws);            // 8 MB  [4096,1024]
    __hip_bfloat16* Wqb = (__hip_bfloat16*)(ws + 8 * MB);   // 2 MB each: Wq,Wk,Wv,Wo
    __hip_bfloat16* Wob = (__hip_bfloat16*)(ws + 14 * MB);
    __hip_bfloat16* Qb  = (__hip_bfloat16*)(ws + 16 * MB);  // 8 MB each, contiguous
    __hip_bfloat16* Kb  = (__hip_bfloat16*)(ws + 24 * MB);
    __hip_bfloat16* Vb  = (__hip_bfloat16*)(ws + 32 * MB);
    __hip_bfloat16* Vt  = (__hip_bfloat16*)(ws + 40 * MB);  // 8 MB [B,H,64,2048]
    __hip_bfloat16* Ab  = (__hip_bfloat16*)(ws + 48 * MB);  // 8 MB attn out

    cast_all<<<dim3(4096, 2), 256, 0, stream>>>(hs, wq, wk, wv, wo, Xb, Wqb);

    // QKV projections with fused hypersphere norm (Q also scaled by qkf*log2e)
    gemm_bt<__hip_bfloat16><<<dim3(32, 8, 3), 256, 0, stream>>>(
        Xb, Wqb, Qb, 1024, 1024, (size_t)1048576, (size_t)4194304, 1, qkf);

    transpose_v<<<dim3(32, 32), 256, 0, stream>>>(Vb, Vt);
    flash_attn<<<512, 256, 0, stream>>>(Qb, Kb, Vt, Ab);

    gemm_bt<float><<<dim3(32, 8, 1), 256, 0, stream>>>(
        Ab, Wob, (float*)d_out, 1024, 1024, (size_t)0, (size_t)0, 0, qkf);
}

// Round 7
// 204.810 us; speedup vs baseline: 1.1087x; 1.1087x over previous
//
#include <hip/hip_runtime.h>
#include <hip/hip_bf16.h>

typedef __attribute__((ext_vector_type(8))) short short8;
typedef __attribute__((ext_vector_type(4))) short short4v;
typedef __attribute__((ext_vector_type(4))) float floatx4;

union BF8 { short8 v; __hip_bfloat16 b[8]; };
union BF4U { ushort4 u; __hip_bfloat16 b[4]; };
union S4U { uint2 u; short4v v; };

__device__ __forceinline__ short8 load8(const __hip_bfloat16* p) {
    return *reinterpret_cast<const short8*>(p);
}
__device__ __forceinline__ short4v load4(const __hip_bfloat16* p) {
    return *reinterpret_cast<const short4v*>(p);
}

__device__ __forceinline__ void storeC(float* p, float v) { *p = v; }
__device__ __forceinline__ void storeC(__hip_bfloat16* p, float v) { *p = __float2bfloat16(v); }

// pack two fp32 -> two bf16 (round-half-up) in one dword: [lo]=a, [hi]=b
__device__ __forceinline__ unsigned pack_bf16(float a, float b) {
    unsigned ua = __float_as_uint(a) + 0x8000u;
    unsigned ub = __float_as_uint(b) + 0x8000u;
    return __builtin_amdgcn_perm(ub, ua, 0x07060302u);
}

// 2^x (v_exp_f32); scale/log2e pre-folded into Q
__device__ __forceinline__ float exp2_fast(float x) {
#if __has_builtin(__builtin_amdgcn_exp2f)
    return __builtin_amdgcn_exp2f(x);
#else
    return __expf(x * 0.6931471805599453f);
#endif
}

// 16x16x16 bf16 MFMA (K=16): A/B are 4 bf16 (2 VGPRs). The C-layout of a
// 16x16 S^T tile (lane: k=lq*4+r, q=lr) IS this shape's A-layout -> PV needs
// no cross-lane transform at all.
#if __has_builtin(__builtin_amdgcn_mfma_f32_16x16x16_bf16)
__device__ __forceinline__ floatx4 mfma16(short4v a, short4v b, floatx4 c) {
    return __builtin_amdgcn_mfma_f32_16x16x16_bf16(a, b, c, 0, 0, 0);
}
#elif __has_builtin(__builtin_amdgcn_mfma_f32_16x16x16bf16_1k)
__device__ __forceinline__ floatx4 mfma16(short4v a, short4v b, floatx4 c) {
    return __builtin_amdgcn_mfma_f32_16x16x16bf16_1k(a, b, c, 0, 0, 0);
}
#else
__device__ __forceinline__ floatx4 mfma16(short4v a, short4v b, floatx4 c) {
    asm volatile("v_mfma_f32_16x16x16_bf16 %0, %1, %2, %0"
                 : "+v"(c) : "v"(a), "v"(b));
    return c;
}
#endif

// async global->LDS, 16B per lane. LDS dest must be wave-uniform base + lane*16.
__device__ __forceinline__ void gload_lds16(const __hip_bfloat16* g, __hip_bfloat16* l) {
    __builtin_amdgcn_global_load_lds(
        (const __attribute__((address_space(1))) void*)g,
        (__attribute__((address_space(3))) void*)l, 16, 0, 0);
}

// -------- fp32 -> bf16 casts: y=0 hidden states (1M float4), y=1 the 4 weights ----
__global__ __launch_bounds__(256) void cast_all(const float* __restrict__ hs,
                                                const float* __restrict__ wq,
                                                const float* __restrict__ wk,
                                                const float* __restrict__ wv,
                                                const float* __restrict__ wo,
                                                __hip_bfloat16* __restrict__ Xb,
                                                __hip_bfloat16* __restrict__ Wb) {
    int i = blockIdx.x * 256 + threadIdx.x;
    const float* src;
    __hip_bfloat16* dst;
    if (blockIdx.y == 0) {
        src = hs; dst = Xb;
    } else {
        int m = i >> 18;
        src = (m == 0) ? wq : (m == 1) ? wk : (m == 2) ? wv : wo;
        src -= (size_t)m * 1048576;
        dst = Wb;
    }
    float4 v = reinterpret_cast<const float4*>(src)[i];
    BF4U u;
    u.b[0] = __float2bfloat16(v.x);
    u.b[1] = __float2bfloat16(v.y);
    u.b[2] = __float2bfloat16(v.z);
    u.b[3] = __float2bfloat16(v.w);
    reinterpret_cast<ushort4*>(dst)[i] = u.u;
}

// ---------------- GEMM: C[M,N] = A[M,K] * B^T  (B given as [N,K] row-major) --------
template <typename OutT>
__global__ __launch_bounds__(256) void gemm_bt(const __hip_bfloat16* __restrict__ A,
                                               const __hip_bfloat16* __restrict__ B0,
                                               OutT* __restrict__ C0,
                                               int N, int Kd,
                                               size_t zsB, size_t zsC,
                                               int normz, const float* __restrict__ scale_p) {
    __shared__ __hip_bfloat16 lA[128 * 32];
    __shared__ __hip_bfloat16 lB[128 * 32];
    const __hip_bfloat16* B = B0 + zsB * blockIdx.z;
    OutT* C = C0 + zsC * blockIdx.z;
    const int t = threadIdx.x;
    const int m0 = blockIdx.x * 128, n0 = blockIdx.y * 128;
    const int w = t >> 6, l = t & 63;
    const int wr = (w >> 1) * 64, wc = (w & 1) * 64;
    const int lr = l & 15, lq = l >> 4;

    const floatx4 zero4 = {0.f, 0.f, 0.f, 0.f};
    floatx4 acc[4][4];
#pragma unroll
    for (int mt = 0; mt < 4; ++mt)
#pragma unroll
        for (int nt = 0; nt < 4; ++nt) acc[mt][nt] = zero4;

    for (int k0 = 0; k0 < Kd; k0 += 32) {
#pragma unroll
        for (int i = 0; i < 2; ++i) {
            int flat = t + i * 256;
            int row = flat >> 2, ch = flat & 3;
            gload_lds16(A + (size_t)(m0 + row) * Kd + k0 + ch * 8, lA + flat * 8);
            gload_lds16(B + (size_t)(n0 + row) * Kd + k0 + ch * 8, lB + flat * 8);
        }
        __syncthreads();
        short8 af[4], bfr[4];
#pragma unroll
        for (int mt = 0; mt < 4; ++mt)
            af[mt] = load8(lA + (wr + mt * 16 + lr) * 32 + lq * 8);
#pragma unroll
        for (int nt = 0; nt < 4; ++nt)
            bfr[nt] = load8(lB + (wc + nt * 16 + lr) * 32 + lq * 8);
#pragma unroll
        for (int mt = 0; mt < 4; ++mt)
#pragma unroll
            for (int nt = 0; nt < 4; ++nt)
                acc[mt][nt] = __builtin_amdgcn_mfma_f32_16x16x32_bf16(
                    af[mt], bfr[nt], acc[mt][nt], 0, 0, 0);
        __syncthreads();
    }

    if (normz && blockIdx.z < 2) {
        const float fac = (blockIdx.z == 0) ? (*scale_p * 1.44269504f) : 1.0f;
#pragma unroll
        for (int mt = 0; mt < 4; ++mt)
#pragma unroll
            for (int r = 0; r < 4; ++r) {
                float ss = 0.f;
#pragma unroll
                for (int nt = 0; nt < 4; ++nt) {
                    float v = acc[mt][nt][r];
                    ss += v * v;
                }
                ss += __shfl_xor(ss, 1, 64);
                ss += __shfl_xor(ss, 2, 64);
                ss += __shfl_xor(ss, 4, 64);
                ss += __shfl_xor(ss, 8, 64);
                float inv = fac / (sqrtf(ss) + 1e-6f);
#pragma unroll
                for (int nt = 0; nt < 4; ++nt) acc[mt][nt][r] *= inv;
            }
    }

#pragma unroll
    for (int mt = 0; mt < 4; ++mt)
#pragma unroll
        for (int nt = 0; nt < 4; ++nt)
#pragma unroll
            for (int r = 0; r < 4; ++r) {
                int row = m0 + wr + mt * 16 + lq * 4 + r;
                int col = n0 + wc + nt * 16 + lr;
                storeC(C + (size_t)row * N + col, acc[mt][nt][r]);
            }
}

// ---------------- V [B,S,H,hd] -> Vt [B,H,hd,S] ----------------
__global__ __launch_bounds__(256) void transpose_v(const __hip_bfloat16* __restrict__ V,
                                                   __hip_bfloat16* __restrict__ Vt) {
    const int S = 2048, D = 1024;
    __shared__ __hip_bfloat16 tile[64][72];
    int t = threadIdx.x;
    int s0 = blockIdx.x * 64;
    int bh = blockIdx.y, b = bh >> 4, h = bh & 15;
    const __hip_bfloat16* src = V + ((size_t)b * S) * D + h * 64;
#pragma unroll
    for (int i = 0; i < 2; ++i) {
        int flat = t + i * 256;
        int sr = flat >> 3, ch = flat & 7;
        *reinterpret_cast<short8*>(&tile[sr][ch * 8]) =
            load8(src + (size_t)(s0 + sr) * D + ch * 8);
    }
    __syncthreads();
    __hip_bfloat16* dst = Vt + (size_t)bh * 64 * S;
#pragma unroll
    for (int i = 0; i < 2; ++i) {
        int flat = t + i * 256;
        int d = flat >> 3, sc = flat & 7;
        BF8 u;
#pragma unroll
        for (int j = 0; j < 8; ++j) u.b[j] = tile[sc * 8 + j][d];
        *reinterpret_cast<short8*>(dst + (size_t)d * S + s0 + sc * 8) = u.v;
    }
}

// ---------------- causal flash attention: paired q-tiles, no LDS in k-loop -------
// S^T = K.Q^T via 16x16x32; P exits in C-layout (lane: k=lq*4+r, q=lr) which IS
// the A-layout of the 16x16x16 MFMA -> PV = two K=16 MFMAs per tile, zero
// cross-lane movement. Epilogue chunk loop MUST be fully unrolled: dynamic
// indexing into oacc sends the accumulator to scratch (R5/R6 lesson: 139 MB
// of scratch writes from one `#pragma unroll 1`).
__global__ __launch_bounds__(256) void flash_attn(const __hip_bfloat16* __restrict__ Q,
                                                  const __hip_bfloat16* __restrict__ K,
                                                  const __hip_bfloat16* __restrict__ Vt,
                                                  __hip_bfloat16* __restrict__ O) {
    const int S = 2048, D = 1024;
    __shared__ __align__(16) char smem[20480];  // epilogue only: 4 x 64x20 fp32
    const int t = threadIdx.x;
    const int w = t >> 6, l = t & 63;
    const int lr = l & 15, lq = l >> 4;
    const int id = blockIdx.x;
    const int bh = (id & 7) * 4 + ((id >> 3) & 3);  // 4 heads per XCD (id%8 ~ XCD)
    const int pr = id >> 5;                          // 0..15 pair index
    const int b = bh >> 4, h = bh & 15;
    const __hip_bfloat16* Qb = Q + ((size_t)b * S) * D + h * 64;
    const __hip_bfloat16* Kb = K + ((size_t)b * S) * D + h * 64;
    const __hip_bfloat16* Vb = Vt + (size_t)bh * 64 * S;
    float* buf = reinterpret_cast<float*>(smem);

#pragma unroll 1
    for (int tile = 0; tile < 2; ++tile) {
        const int jq = (tile == 0) ? (31 - pr) : pr;
        const int q0 = jq * 64;

        short8 bq[4][2];
#pragma unroll
        for (int nt = 0; nt < 4; ++nt)
#pragma unroll
            for (int kt = 0; kt < 2; ++kt)
                bq[nt][kt] = load8(Qb + (size_t)(q0 + nt * 16 + lr) * D + kt * 32 + lq * 8);

        const floatx4 zero4 = {0.f, 0.f, 0.f, 0.f};
        floatx4 oacc[4][4];
        float lsum[4] = {0.f, 0.f, 0.f, 0.f};
#pragma unroll
        for (int mt = 0; mt < 4; ++mt)
#pragma unroll
            for (int nt = 0; nt < 4; ++nt) oacc[mt][nt] = zero4;

        const int klast = 2 * jq + 1;  // inclusive last 32-wide k-step
        const int kmask = 2 * jq;      // steps >= kmask need the causal mask

        if (w <= klast) {
#pragma unroll 1
            for (int ks = w; ks <= klast; ks += 4) {
                const int k0 = ks * 32;
                short8 bk[2][2];
#pragma unroll
                for (int mt = 0; mt < 2; ++mt)
#pragma unroll
                    for (int kt = 0; kt < 2; ++kt)
                        bk[mt][kt] = load8(Kb + (size_t)(k0 + mt * 16 + lr) * D + kt * 32 + lq * 8);
                // S^T = K.Q^T
                floatx4 sacc[2][4];
#pragma unroll
                for (int mt = 0; mt < 2; ++mt)
#pragma unroll
                    for (int nt = 0; nt < 4; ++nt) sacc[mt][nt] = zero4;
#pragma unroll
                for (int mt = 0; mt < 2; ++mt)
#pragma unroll
                    for (int nt = 0; nt < 4; ++nt)
#pragma unroll
                        for (int kt = 0; kt < 2; ++kt)
                            sacc[mt][nt] = __builtin_amdgcn_mfma_f32_16x16x32_bf16(
                                bk[mt][kt], bq[nt][kt], sacc[mt][nt], 0, 0, 0);
                // V B-fragments for the two K=16 PV MFMAs
                short4v bv[2][4];
#pragma unroll
                for (int mt = 0; mt < 2; ++mt)
#pragma unroll
                    for (int ntd = 0; ntd < 4; ++ntd)
                        bv[mt][ntd] = load4(Vb + (size_t)(ntd * 16 + lr) * S + k0 + mt * 16 + lq * 4);
                const bool domask = ks >= kmask;  // wave-uniform
                short4v ap[2][4];
#pragma unroll
                for (int mt = 0; mt < 2; ++mt)
#pragma unroll
                    for (int nt = 0; nt < 4; ++nt) {
                        float p0 = exp2_fast(sacc[mt][nt][0]);
                        float p1 = exp2_fast(sacc[mt][nt][1]);
                        float p2 = exp2_fast(sacc[mt][nt][2]);
                        float p3 = exp2_fast(sacc[mt][nt][3]);
                        if (domask) {
                            const int qg = q0 + nt * 16 + lr;
                            const int kb = k0 + mt * 16 + lq * 4;
                            p0 = (kb + 0 <= qg) ? p0 : 0.f;
                            p1 = (kb + 1 <= qg) ? p1 : 0.f;
                            p2 = (kb + 2 <= qg) ? p2 : 0.f;
                            p3 = (kb + 3 <= qg) ? p3 : 0.f;
                        }
                        lsum[nt] += (p0 + p1) + (p2 + p3);
                        S4U u;
                        u.u.x = pack_bf16(p0, p1);
                        u.u.y = pack_bf16(p2, p3);
                        ap[mt][nt] = u.v;
                    }
                // PV: oacc[q-tile][d-tile] += P(K=16) . V(K=16), mt = k-subtile
#pragma unroll
                for (int mt = 0; mt < 2; ++mt)
#pragma unroll
                    for (int ntq = 0; ntq < 4; ++ntq)
#pragma unroll
                        for (int ntd = 0; ntd < 4; ++ntd)
                            oacc[ntq][ntd] = mfma16(ap[mt][ntq], bv[mt][ntd], oacc[ntq][ntd]);
            }
        }

        // reduce lsum over the 4 lq-quads (q index = nt*16+lr is lr-indexed)
#pragma unroll
        for (int nt = 0; nt < 4; ++nt) {
            float s = lsum[nt];
            s += __shfl_xor(s, 16, 64);
            s += __shfl_xor(s, 32, 64);
            lsum[nt] = s;
        }

        // ---- cross-wave reduce: d in 4 chunks of 16, buf[w][64][20] fp32 ----
        // FULLY UNROLLED so oacc indexing stays compile-time-constant.
        const int row = t >> 2, c0 = (t & 3) * 4;
        __hip_bfloat16* Ob = O + ((size_t)b * S) * D + h * 64;
        float inv = 0.f;
        __syncthreads();  // previous tile's epilogue reads done before overwrite
#pragma unroll
        for (int chunk = 0; chunk < 4; ++chunk) {
#pragma unroll
            for (int mtq = 0; mtq < 4; ++mtq)
#pragma unroll
                for (int r = 0; r < 4; ++r)
                    buf[w * 1280 + (mtq * 16 + lq * 4 + r) * 20 + lr] = oacc[mtq][chunk][r];
            if (chunk == 0 && lq == 0) {
#pragma unroll
                for (int nt = 0; nt < 4; ++nt)
                    buf[w * 1280 + (nt * 16 + lr) * 20 + 16] = lsum[nt];
            }
            __syncthreads();
            if (chunk == 0) {
                float Lt = buf[row * 20 + 16] + buf[1280 + row * 20 + 16] +
                           buf[2560 + row * 20 + 16] + buf[3840 + row * 20 + 16];
                inv = 1.f / Lt;
            }
            float4 a = {0.f, 0.f, 0.f, 0.f};
#pragma unroll
            for (int w2 = 0; w2 < 4; ++w2) {
                float4 v = *reinterpret_cast<const float4*>(buf + w2 * 1280 + row * 20 + c0);
                a.x += v.x; a.y += v.y; a.z += v.z; a.w += v.w;
            }
            uint2 d;
            d.x = pack_bf16(a.x * inv, a.y * inv);
            d.y = pack_bf16(a.z * inv, a.w * inv);
            *reinterpret_cast<uint2*>(Ob + (size_t)(q0 + row) * D + chunk * 16 + c0) = d;
            if (chunk < 3) __syncthreads();  // WAR before next chunk's writes
        }
    }
}

extern "C" void kernel_launch(void* const* d_in, const int* in_sizes, int n_in,
                              void* d_out, int out_size, void* d_ws, size_t ws_size,
                              hipStream_t stream) {
    const float* hs  = (const float*)d_in[0];  // [2,2048,1024]
    const float* wq  = (const float*)d_in[1];  // [1024,1024]
    const float* wk  = (const float*)d_in[2];
    const float* wv  = (const float*)d_in[3];
    const float* wo  = (const float*)d_in[4];
    const float* qkf = (const float*)d_in[5];  // scalar

    char* ws = (char*)d_ws;
    const size_t MB = 1024 * 1024;
    __hip_bfloat16* Xb  = (__hip_bfloat16*)(ws);            // 8 MB  [4096,1024]
    __hip_bfloat16* Wqb = (__hip_bfloat16*)(ws + 8 * MB);   // 2 MB each: Wq,Wk,Wv,Wo
    __hip_bfloat16* Wob = (__hip_bfloat16*)(ws + 14 * MB);
    __hip_bfloat16* Qb  = (__hip_bfloat16*)(ws + 16 * MB);  // 8 MB each, contiguous
    __hip_bfloat16* Kb  = (__hip_bfloat16*)(ws + 24 * MB);
    __hip_bfloat16* Vb  = (__hip_bfloat16*)(ws + 32 * MB);
    __hip_bfloat16* Vt  = (__hip_bfloat16*)(ws + 40 * MB);  // 8 MB [B,H,64,2048]
    __hip_bfloat16* Ab  = (__hip_bfloat16*)(ws + 48 * MB);  // 8 MB attn out

    cast_all<<<dim3(4096, 2), 256, 0, stream>>>(hs, wq, wk, wv, wo, Xb, Wqb);

    // QKV projections with fused hypersphere norm (Q also scaled by qkf*log2e)
    gemm_bt<__hip_bfloat16><<<dim3(32, 8, 3), 256, 0, stream>>>(
        Xb, Wqb, Qb, 1024, 1024, (size_t)1048576, (size_t)4194304, 1, qkf);

    transpose_v<<<dim3(32, 32), 256, 0, stream>>>(Vb, Vt);
    flash_attn<<<512, 256, 0, stream>>>(Qb, Kb, Vt, Ab);

    gemm_bt<float><<<dim3(32, 8, 1), 256, 0, stream>>>(
        Ab, Wob, (float*)d_out, 1024, 1024, (size_t)0, (size_t)0, 0, qkf);
}

// Round 8
// 184.590 us; speedup vs baseline: 1.2302x; 1.1095x over previous
//
#include <hip/hip_runtime.h>
#include <hip/hip_bf16.h>

typedef __attribute__((ext_vector_type(8))) short short8;
typedef __attribute__((ext_vector_type(4))) short short4v;
typedef __attribute__((ext_vector_type(4))) float floatx4;

union BF8 { short8 v; __hip_bfloat16 b[8]; };
union BF4U { ushort4 u; __hip_bfloat16 b[4]; };
union S4U { uint2 u; short4v v; };

__device__ __forceinline__ short8 load8(const __hip_bfloat16* p) {
    return *reinterpret_cast<const short8*>(p);
}
__device__ __forceinline__ short4v load4(const __hip_bfloat16* p) {
    return *reinterpret_cast<const short4v*>(p);
}

__device__ __forceinline__ void storeC(float* p, float v) { *p = v; }
__device__ __forceinline__ void storeC(__hip_bfloat16* p, float v) { *p = __float2bfloat16(v); }

// pack two fp32 -> two bf16 (round-half-up) in one dword: [lo]=a, [hi]=b
__device__ __forceinline__ unsigned pack_bf16(float a, float b) {
    unsigned ua = __float_as_uint(a) + 0x8000u;
    unsigned ub = __float_as_uint(b) + 0x8000u;
    return __builtin_amdgcn_perm(ub, ua, 0x07060302u);
}

// 2^x (v_exp_f32); scale/log2e pre-folded into Q
__device__ __forceinline__ float exp2_fast(float x) {
#if __has_builtin(__builtin_amdgcn_exp2f)
    return __builtin_amdgcn_exp2f(x);
#else
    return __expf(x * 0.6931471805599453f);
#endif
}

// 16x16x16 bf16 MFMA (K=16): the C-layout of a 16x16 S^T tile (lane: k=lq*4+r,
// q=lr) IS this shape's A-layout -> PV needs no cross-lane transform.
#if __has_builtin(__builtin_amdgcn_mfma_f32_16x16x16_bf16)
__device__ __forceinline__ floatx4 mfma16(short4v a, short4v b, floatx4 c) {
    return __builtin_amdgcn_mfma_f32_16x16x16_bf16(a, b, c, 0, 0, 0);
}
#elif __has_builtin(__builtin_amdgcn_mfma_f32_16x16x16bf16_1k)
__device__ __forceinline__ floatx4 mfma16(short4v a, short4v b, floatx4 c) {
    return __builtin_amdgcn_mfma_f32_16x16x16bf16_1k(a, b, c, 0, 0, 0);
}
#else
__device__ __forceinline__ floatx4 mfma16(short4v a, short4v b, floatx4 c) {
    asm volatile("v_mfma_f32_16x16x16_bf16 %0, %1, %2, %0"
                 : "+v"(c) : "v"(a), "v"(b));
    return c;
}
#endif

// async global->LDS, 16B per lane. LDS dest must be wave-uniform base + lane*16.
__device__ __forceinline__ void gload_lds16(const __hip_bfloat16* g, __hip_bfloat16* l) {
    __builtin_amdgcn_global_load_lds(
        (const __attribute__((address_space(1))) void*)g,
        (__attribute__((address_space(3))) void*)l, 16, 0, 0);
}

// -------- fp32 -> bf16 casts: y=0 hidden states (1M float4), y=1 the 4 weights ----
__global__ __launch_bounds__(256) void cast_all(const float* __restrict__ hs,
                                                const float* __restrict__ wq,
                                                const float* __restrict__ wk,
                                                const float* __restrict__ wv,
                                                const float* __restrict__ wo,
                                                __hip_bfloat16* __restrict__ Xb,
                                                __hip_bfloat16* __restrict__ Wb) {
    int i = blockIdx.x * 256 + threadIdx.x;
    const float* src;
    __hip_bfloat16* dst;
    if (blockIdx.y == 0) {
        src = hs; dst = Xb;
    } else {
        int m = i >> 18;
        src = (m == 0) ? wq : (m == 1) ? wk : (m == 2) ? wv : wo;
        src -= (size_t)m * 1048576;
        dst = Wb;
    }
    float4 v = reinterpret_cast<const float4*>(src)[i];
    BF4U u;
    u.b[0] = __float2bfloat16(v.x);
    u.b[1] = __float2bfloat16(v.y);
    u.b[2] = __float2bfloat16(v.z);
    u.b[3] = __float2bfloat16(v.w);
    reinterpret_cast<ushort4*>(dst)[i] = u.u;
}

// ---------------- GEMM: C[M,N] = A[M,K] * B^T  (B given as [N,K] row-major) --------
template <typename OutT>
__global__ __launch_bounds__(256) void gemm_bt(const __hip_bfloat16* __restrict__ A,
                                               const __hip_bfloat16* __restrict__ B0,
                                               OutT* __restrict__ C0,
                                               int N, int Kd,
                                               size_t zsB, size_t zsC,
                                               int normz, const float* __restrict__ scale_p) {
    __shared__ __hip_bfloat16 lA[128 * 32];
    __shared__ __hip_bfloat16 lB[128 * 32];
    const __hip_bfloat16* B = B0 + zsB * blockIdx.z;
    OutT* C = C0 + zsC * blockIdx.z;
    const int t = threadIdx.x;
    const int m0 = blockIdx.x * 128, n0 = blockIdx.y * 128;
    const int w = t >> 6, l = t & 63;
    const int wr = (w >> 1) * 64, wc = (w & 1) * 64;
    const int lr = l & 15, lq = l >> 4;

    const floatx4 zero4 = {0.f, 0.f, 0.f, 0.f};
    floatx4 acc[4][4];
#pragma unroll
    for (int mt = 0; mt < 4; ++mt)
#pragma unroll
        for (int nt = 0; nt < 4; ++nt) acc[mt][nt] = zero4;

    for (int k0 = 0; k0 < Kd; k0 += 32) {
#pragma unroll
        for (int i = 0; i < 2; ++i) {
            int flat = t + i * 256;
            int row = flat >> 2, ch = flat & 3;
            gload_lds16(A + (size_t)(m0 + row) * Kd + k0 + ch * 8, lA + flat * 8);
            gload_lds16(B + (size_t)(n0 + row) * Kd + k0 + ch * 8, lB + flat * 8);
        }
        __syncthreads();
        short8 af[4], bfr[4];
#pragma unroll
        for (int mt = 0; mt < 4; ++mt)
            af[mt] = load8(lA + (wr + mt * 16 + lr) * 32 + lq * 8);
#pragma unroll
        for (int nt = 0; nt < 4; ++nt)
            bfr[nt] = load8(lB + (wc + nt * 16 + lr) * 32 + lq * 8);
#pragma unroll
        for (int mt = 0; mt < 4; ++mt)
#pragma unroll
            for (int nt = 0; nt < 4; ++nt)
                acc[mt][nt] = __builtin_amdgcn_mfma_f32_16x16x32_bf16(
                    af[mt], bfr[nt], acc[mt][nt], 0, 0, 0);
        __syncthreads();
    }

    if (normz && blockIdx.z < 2) {
        const float fac = (blockIdx.z == 0) ? (*scale_p * 1.44269504f) : 1.0f;
#pragma unroll
        for (int mt = 0; mt < 4; ++mt)
#pragma unroll
            for (int r = 0; r < 4; ++r) {
                float ss = 0.f;
#pragma unroll
                for (int nt = 0; nt < 4; ++nt) {
                    float v = acc[mt][nt][r];
                    ss += v * v;
                }
                ss += __shfl_xor(ss, 1, 64);
                ss += __shfl_xor(ss, 2, 64);
                ss += __shfl_xor(ss, 4, 64);
                ss += __shfl_xor(ss, 8, 64);
                float inv = fac / (sqrtf(ss) + 1e-6f);
#pragma unroll
                for (int nt = 0; nt < 4; ++nt) acc[mt][nt][r] *= inv;
            }
    }

#pragma unroll
    for (int mt = 0; mt < 4; ++mt)
#pragma unroll
        for (int nt = 0; nt < 4; ++nt)
#pragma unroll
            for (int r = 0; r < 4; ++r) {
                int row = m0 + wr + mt * 16 + lq * 4 + r;
                int col = n0 + wc + nt * 16 + lr;
                storeC(C + (size_t)row * N + col, acc[mt][nt][r]);
            }
}

// ---------------- V [B,S,H,hd] -> Vt [B,H,hd,S] ----------------
__global__ __launch_bounds__(256) void transpose_v(const __hip_bfloat16* __restrict__ V,
                                                   __hip_bfloat16* __restrict__ Vt) {
    const int S = 2048, D = 1024;
    __shared__ __hip_bfloat16 tile[64][72];
    int t = threadIdx.x;
    int s0 = blockIdx.x * 64;
    int bh = blockIdx.y, b = bh >> 4, h = bh & 15;
    const __hip_bfloat16* src = V + ((size_t)b * S) * D + h * 64;
#pragma unroll
    for (int i = 0; i < 2; ++i) {
        int flat = t + i * 256;
        int sr = flat >> 3, ch = flat & 7;
        *reinterpret_cast<short8*>(&tile[sr][ch * 8]) =
            load8(src + (size_t)(s0 + sr) * D + ch * 8);
    }
    __syncthreads();
    __hip_bfloat16* dst = Vt + (size_t)bh * 64 * S;
#pragma unroll
    for (int i = 0; i < 2; ++i) {
        int flat = t + i * 256;
        int d = flat >> 3, sc = flat & 7;
        BF8 u;
#pragma unroll
        for (int j = 0; j < 8; ++j) u.b[j] = tile[sc * 8 + j][d];
        *reinterpret_cast<short8*>(dst + (size_t)d * S + s0 + sc * 8) = u.v;
    }
}

// ---------------- causal flash attention: LDS-staged K/V, paired q-tiles ---------
// R7 lesson: direct-from-global fragment loads hit 64 cache lines/instr (lanes
// stride 2-4 KB) -> TA-pipe serialization was the limiter. Now each wave DMAs its
// K/V step-tiles into private LDS double buffers with COALESCED global_load_lds
// (16 lines/instr), XOR-swizzled so fragment ds_reads are conflict-free despite
// the unpadded lane*16 DMA layout. Prefetch of step ks+4 is issued after the
// current fragment reads, hiding under compute. No barriers in the k-loop.
__global__ __launch_bounds__(256, 2) void flash_attn(const __hip_bfloat16* __restrict__ Q,
                                                     const __hip_bfloat16* __restrict__ K,
                                                     const __hip_bfloat16* __restrict__ Vt,
                                                     __hip_bfloat16* __restrict__ O) {
    const int S = 2048, D = 1024;
    // per wave 16 KB: K dbuf 2x4KB + V dbuf 2x4KB; epilogue reuses first 20 KB
    __shared__ __align__(16) char smem[65536];
    const int t = threadIdx.x;
    const int w = t >> 6, l = t & 63;
    const int lr = l & 15, lq = l >> 4;
    const int id = blockIdx.x;
    const int bh = (id & 7) * 4 + ((id >> 3) & 3);  // 4 heads per XCD (id%8 ~ XCD)
    const int pr = id >> 5;                          // 0..15 pair index
    const int b = bh >> 4, h = bh & 15;
    const __hip_bfloat16* Qb = Q + ((size_t)b * S) * D + h * 64;
    const __hip_bfloat16* Kb = K + ((size_t)b * S) * D + h * 64;
    const __hip_bfloat16* Vb = Vt + (size_t)bh * 64 * S;
    __hip_bfloat16* wbase = reinterpret_cast<__hip_bfloat16*>(smem) + w * 8192;
    float* buf = reinterpret_cast<float*>(smem);

    // DMA lane roles. K tile: 32 rows x 8 segs(16B); LDS[r][s] = Gl[r][s^(r&7)].
    // V tile: 64 rows x 4 segs(16B);                 LDS[r][s] = Gl[r][s^(r&3)].
    const int kr = l >> 3, ksg = (l & 7) ^ (kr & 7);
    const int vr = l >> 2, vsg = (l & 3) ^ (vr & 3);

#pragma unroll 1
    for (int tile = 0; tile < 2; ++tile) {
        const int jq = (tile == 0) ? (31 - pr) : pr;
        const int q0 = jq * 64;

        short8 bq[4][2];
#pragma unroll
        for (int nt = 0; nt < 4; ++nt)
#pragma unroll
            for (int kt = 0; kt < 2; ++kt)
                bq[nt][kt] = load8(Qb + (size_t)(q0 + nt * 16 + lr) * D + kt * 32 + lq * 8);

        const floatx4 zero4 = {0.f, 0.f, 0.f, 0.f};
        floatx4 oacc[4][4];
        float lsum[4] = {0.f, 0.f, 0.f, 0.f};
#pragma unroll
        for (int mt = 0; mt < 4; ++mt)
#pragma unroll
            for (int nt = 0; nt < 4; ++nt) oacc[mt][nt] = zero4;

        const int klast = 2 * jq + 1;
        const int kmask = 2 * jq;

        if (w <= klast) {
            // stage first step into buffer 0 (4 K-instr + 4 V-instr, coalesced)
            {
                const int k0 = w * 32;
#pragma unroll
                for (int i = 0; i < 4; ++i)
                    gload_lds16(Kb + (size_t)(k0 + i * 8 + kr) * D + ksg * 8,
                                wbase + i * 512 + l * 8);
#pragma unroll
                for (int i = 0; i < 4; ++i)
                    gload_lds16(Vb + (size_t)(i * 16 + vr) * S + k0 + vsg * 8,
                                wbase + 4096 + i * 512 + l * 8);
            }
            int p = 0;
#pragma unroll 1
            for (int ks = w; ks <= klast; ks += 4) {
                const int k0 = ks * 32;
                // staged[p] (and any older vmem) complete before LDS reads
                asm volatile("s_waitcnt vmcnt(0)" ::: "memory");
                const __hip_bfloat16* kb = wbase + p * 2048;
                const __hip_bfloat16* vb = wbase + 4096 + p * 2048;
                short8 bk[2][2];
#pragma unroll
                for (int mt = 0; mt < 2; ++mt)
#pragma unroll
                    for (int kt = 0; kt < 2; ++kt) {
                        const int rl = mt * 16 + lr;
                        const int sg = (kt * 4 + lq) ^ (rl & 7);
                        bk[mt][kt] = load8(kb + rl * 64 + sg * 8);
                    }
                short4v bv[2][4];
#pragma unroll
                for (int mt = 0; mt < 2; ++mt)
#pragma unroll
                    for (int ntd = 0; ntd < 4; ++ntd) {
                        const int rl = ntd * 16 + lr;
                        const int sg = (mt * 2 + (lq >> 1)) ^ (rl & 3);
                        bv[mt][ntd] = load4(vb + rl * 32 + sg * 8 + (lq & 1) * 4);
                    }
                // prefetch next step into buffer p^1 (latency hides under compute)
                if (ks + 4 <= klast) {
                    const int kn = (ks + 4) * 32;
                    __hip_bfloat16* nb = wbase + (p ^ 1) * 2048;
#pragma unroll
                    for (int i = 0; i < 4; ++i)
                        gload_lds16(Kb + (size_t)(kn + i * 8 + kr) * D + ksg * 8,
                                    nb + i * 512 + l * 8);
#pragma unroll
                    for (int i = 0; i < 4; ++i)
                        gload_lds16(Vb + (size_t)(i * 16 + vr) * S + kn + vsg * 8,
                                    nb + 4096 + i * 512 + l * 8);
                }
                // S^T = K.Q^T
                floatx4 sacc[2][4];
#pragma unroll
                for (int mt = 0; mt < 2; ++mt)
#pragma unroll
                    for (int nt = 0; nt < 4; ++nt) sacc[mt][nt] = zero4;
#pragma unroll
                for (int mt = 0; mt < 2; ++mt)
#pragma unroll
                    for (int nt = 0; nt < 4; ++nt)
#pragma unroll
                        for (int kt = 0; kt < 2; ++kt)
                            sacc[mt][nt] = __builtin_amdgcn_mfma_f32_16x16x32_bf16(
                                bk[mt][kt], bq[nt][kt], sacc[mt][nt], 0, 0, 0);
                const bool domask = ks >= kmask;  // wave-uniform
                short4v ap[2][4];
#pragma unroll
                for (int mt = 0; mt < 2; ++mt)
#pragma unroll
                    for (int nt = 0; nt < 4; ++nt) {
                        float p0 = exp2_fast(sacc[mt][nt][0]);
                        float p1 = exp2_fast(sacc[mt][nt][1]);
                        float p2 = exp2_fast(sacc[mt][nt][2]);
                        float p3 = exp2_fast(sacc[mt][nt][3]);
                        if (domask) {
                            const int qg = q0 + nt * 16 + lr;
                            const int kb2 = k0 + mt * 16 + lq * 4;
                            p0 = (kb2 + 0 <= qg) ? p0 : 0.f;
                            p1 = (kb2 + 1 <= qg) ? p1 : 0.f;
                            p2 = (kb2 + 2 <= qg) ? p2 : 0.f;
                            p3 = (kb2 + 3 <= qg) ? p3 : 0.f;
                        }
                        lsum[nt] += (p0 + p1) + (p2 + p3);
                        S4U u;
                        u.u.x = pack_bf16(p0, p1);
                        u.u.y = pack_bf16(p2, p3);
                        ap[mt][nt] = u.v;
                    }
                // PV: two K=16 MFMAs per (q,d) tile; mt = k-subtile
#pragma unroll
                for (int mt = 0; mt < 2; ++mt)
#pragma unroll
                    for (int ntq = 0; ntq < 4; ++ntq)
#pragma unroll
                        for (int ntd = 0; ntd < 4; ++ntd)
                            oacc[ntq][ntd] = mfma16(ap[mt][ntq], bv[mt][ntd], oacc[ntq][ntd]);
                p ^= 1;
            }
        }

        // reduce lsum over the 4 lq-quads
#pragma unroll
        for (int nt = 0; nt < 4; ++nt) {
            float s = lsum[nt];
            s += __shfl_xor(s, 16, 64);
            s += __shfl_xor(s, 32, 64);
            lsum[nt] = s;
        }

        // ---- cross-wave reduce: d in 4 chunks of 16, buf[w][64][20] fp32 ----
        // FULLY UNROLLED: dynamic oacc indexing would spill the accumulator
        // to scratch (R5/R6 lesson: 139 MB scratch writes from `unroll 1`).
        const int row = t >> 2, c0 = (t & 3) * 4;
        __hip_bfloat16* Ob = O + ((size_t)b * S) * D + h * 64;
        float inv = 0.f;
        __syncthreads();  // previous tile's epilogue reads done before overwrite
#pragma unroll
        for (int chunk = 0; chunk < 4; ++chunk) {
#pragma unroll
            for (int mtq = 0; mtq < 4; ++mtq)
#pragma unroll
                for (int r = 0; r < 4; ++r)
                    buf[w * 1280 + (mtq * 16 + lq * 4 + r) * 20 + lr] = oacc[mtq][chunk][r];
            if (chunk == 0 && lq == 0) {
#pragma unroll
                for (int nt = 0; nt < 4; ++nt)
                    buf[w * 1280 + (nt * 16 + lr) * 20 + 16] = lsum[nt];
            }
            __syncthreads();
            if (chunk == 0) {
                float Lt = buf[row * 20 + 16] + buf[1280 + row * 20 + 16] +
                           buf[2560 + row * 20 + 16] + buf[3840 + row * 20 + 16];
                inv = 1.f / Lt;
            }
            float4 a = {0.f, 0.f, 0.f, 0.f};
#pragma unroll
            for (int w2 = 0; w2 < 4; ++w2) {
                float4 v = *reinterpret_cast<const float4*>(buf + w2 * 1280 + row * 20 + c0);
                a.x += v.x; a.y += v.y; a.z += v.z; a.w += v.w;
            }
            uint2 d;
            d.x = pack_bf16(a.x * inv, a.y * inv);
            d.y = pack_bf16(a.z * inv, a.w * inv);
            *reinterpret_cast<uint2*>(Ob + (size_t)(q0 + row) * D + chunk * 16 + c0) = d;
            if (chunk < 3) __syncthreads();  // WAR before next chunk's writes
        }
    }
}

extern "C" void kernel_launch(void* const* d_in, const int* in_sizes, int n_in,
                              void* d_out, int out_size, void* d_ws, size_t ws_size,
                              hipStream_t stream) {
    const float* hs  = (const float*)d_in[0];  // [2,2048,1024]
    const float* wq  = (const float*)d_in[1];  // [1024,1024]
    const float* wk  = (const float*)d_in[2];
    const float* wv  = (const float*)d_in[3];
    const float* wo  = (const float*)d_in[4];
    const float* qkf = (const float*)d_in[5];  // scalar

    char* ws = (char*)d_ws;
    const size_t MB = 1024 * 1024;
    __hip_bfloat16* Xb  = (__hip_bfloat16*)(ws);            // 8 MB  [4096,1024]
    __hip_bfloat16* Wqb = (__hip_bfloat16*)(ws + 8 * MB);   // 2 MB each: Wq,Wk,Wv,Wo
    __hip_bfloat16* Wob = (__hip_bfloat16*)(ws + 14 * MB);
    __hip_bfloat16* Qb  = (__hip_bfloat16*)(ws + 16 * MB);  // 8 MB each, contiguous
    __hip_bfloat16* Kb  = (__hip_bfloat16*)(ws + 24 * MB);
    __hip_bfloat16* Vb  = (__hip_bfloat16*)(ws + 32 * MB);
    __hip_bfloat16* Vt  = (__hip_bfloat16*)(ws + 40 * MB);  // 8 MB [B,H,64,2048]
    __hip_bfloat16* Ab  = (__hip_bfloat16*)(ws + 48 * MB);  // 8 MB attn out

    cast_all<<<dim3(4096, 2), 256, 0, stream>>>(hs, wq, wk, wv, wo, Xb, Wqb);

    // QKV projections with fused hypersphere norm (Q also scaled by qkf*log2e)
    gemm_bt<__hip_bfloat16><<<dim3(32, 8, 3), 256, 0, stream>>>(
        Xb, Wqb, Qb, 1024, 1024, (size_t)1048576, (size_t)4194304, 1, qkf);

    transpose_v<<<dim3(32, 32), 256, 0, stream>>>(Vb, Vt);
    flash_attn<<<512, 256, 0, stream>>>(Qb, Kb, Vt, Ab);

    gemm_bt<float><<<dim3(32, 8, 1), 256, 0, stream>>>(
        Ab, Wob, (float*)d_out, 1024, 1024, (size_t)0, (size_t)0, 0, qkf);
}

// Round 9
// 180.718 us; speedup vs baseline: 1.2565x; 1.0214x over previous
//
#include <hip/hip_runtime.h>
#include <hip/hip_bf16.h>

typedef __attribute__((ext_vector_type(8))) short short8;
typedef __attribute__((ext_vector_type(4))) short short4v;
typedef __attribute__((ext_vector_type(4))) float floatx4;

union BF8 { short8 v; __hip_bfloat16 b[8]; };
union BF4U { ushort4 u; __hip_bfloat16 b[4]; };
union S4U { uint2 u; short4v v; };

__device__ __forceinline__ short8 load8(const __hip_bfloat16* p) {
    return *reinterpret_cast<const short8*>(p);
}
__device__ __forceinline__ short4v load4(const __hip_bfloat16* p) {
    return *reinterpret_cast<const short4v*>(p);
}

__device__ __forceinline__ void storeC(float* p, float v) { *p = v; }
__device__ __forceinline__ void storeC(__hip_bfloat16* p, float v) { *p = __float2bfloat16(v); }

// pack two fp32 -> two bf16 (round-half-up) in one dword: [lo]=a, [hi]=b
__device__ __forceinline__ unsigned pack_bf16(float a, float b) {
    unsigned ua = __float_as_uint(a) + 0x8000u;
    unsigned ub = __float_as_uint(b) + 0x8000u;
    return __builtin_amdgcn_perm(ub, ua, 0x07060302u);
}

// 2^x (v_exp_f32); scale/log2e pre-folded into Q
__device__ __forceinline__ float exp2_fast(float x) {
#if __has_builtin(__builtin_amdgcn_exp2f)
    return __builtin_amdgcn_exp2f(x);
#else
    return __expf(x * 0.6931471805599453f);
#endif
}

// 16x16x16 bf16 MFMA (K=16): the C-layout of a 16x16 S^T tile (lane: k=lq*4+r,
// q=lr) IS this shape's A-layout -> PV needs no cross-lane transform.
#if __has_builtin(__builtin_amdgcn_mfma_f32_16x16x16_bf16)
__device__ __forceinline__ floatx4 mfma16(short4v a, short4v b, floatx4 c) {
    return __builtin_amdgcn_mfma_f32_16x16x16_bf16(a, b, c, 0, 0, 0);
}
#elif __has_builtin(__builtin_amdgcn_mfma_f32_16x16x16bf16_1k)
__device__ __forceinline__ floatx4 mfma16(short4v a, short4v b, floatx4 c) {
    return __builtin_amdgcn_mfma_f32_16x16x16bf16_1k(a, b, c, 0, 0, 0);
}
#else
__device__ __forceinline__ floatx4 mfma16(short4v a, short4v b, floatx4 c) {
    asm volatile("v_mfma_f32_16x16x16_bf16 %0, %1, %2, %0"
                 : "+v"(c) : "v"(a), "v"(b));
    return c;
}
#endif

// async global->LDS, 16B per lane. LDS dest must be wave-uniform base + lane*16.
__device__ __forceinline__ void gload_lds16(const __hip_bfloat16* g, __hip_bfloat16* l) {
    __builtin_amdgcn_global_load_lds(
        (const __attribute__((address_space(1))) void*)g,
        (__attribute__((address_space(3))) void*)l, 16, 0, 0);
}

// -------- fp32 -> bf16 casts: y=0 hidden states (1M float4), y=1 the 4 weights ----
__global__ __launch_bounds__(256) void cast_all(const float* __restrict__ hs,
                                                const float* __restrict__ wq,
                                                const float* __restrict__ wk,
                                                const float* __restrict__ wv,
                                                const float* __restrict__ wo,
                                                __hip_bfloat16* __restrict__ Xb,
                                                __hip_bfloat16* __restrict__ Wb) {
    int i = blockIdx.x * 256 + threadIdx.x;
    const float* src;
    __hip_bfloat16* dst;
    if (blockIdx.y == 0) {
        src = hs; dst = Xb;
    } else {
        int m = i >> 18;
        src = (m == 0) ? wq : (m == 1) ? wk : (m == 2) ? wv : wo;
        src -= (size_t)m * 1048576;
        dst = Wb;
    }
    float4 v = reinterpret_cast<const float4*>(src)[i];
    BF4U u;
    u.b[0] = __float2bfloat16(v.x);
    u.b[1] = __float2bfloat16(v.y);
    u.b[2] = __float2bfloat16(v.z);
    u.b[3] = __float2bfloat16(v.w);
    reinterpret_cast<ushort4*>(dst)[i] = u.u;
}

// ------- fused QKV projection GEMM (B^T form), 128x128 tiles, BK=32 --------------
// z=0: Q = X.Wq^T, per-head L2 norm, scaled by qkf*log2e -> Qb [4096,1024]
// z=1: K = X.Wk^T, per-head L2 norm                      -> Kb [4096,1024]
// z=2: Vt = (Wv.X^T) stored row-major = V^T directly     -> Vt [B=2][1024 e][2048 s]
//      (256 blocks remapped to an 8x32 tile grid; kills the transpose_v kernel)
__global__ __launch_bounds__(256) void gemm_qkv(const __hip_bfloat16* __restrict__ Xb,
                                                const __hip_bfloat16* __restrict__ Wqkv,
                                                __hip_bfloat16* __restrict__ Qb,
                                                __hip_bfloat16* __restrict__ Kb,
                                                __hip_bfloat16* __restrict__ Vt,
                                                const float* __restrict__ scale_p) {
    __shared__ __hip_bfloat16 lA[128 * 32];
    __shared__ __hip_bfloat16 lB[128 * 32];
    const int z = blockIdx.z;
    const __hip_bfloat16* A;
    const __hip_bfloat16* B;
    int m0, n0;
    if (z < 2) {
        A = Xb;                                // [4096,1024]
        B = Wqkv + (size_t)z * 1048576;        // [1024,1024]
        m0 = blockIdx.x * 128;
        n0 = blockIdx.y * 128;
    } else {
        A = Wqkv + (size_t)2 * 1048576;        // Wv [1024,1024]
        B = Xb;                                // [4096,1024]
        m0 = (blockIdx.x & 7) * 128;                       // e-tiles: 8
        n0 = (((blockIdx.x >> 3) * 8) + blockIdx.y) * 128; // bs-tiles: 32
    }
    const int Kd = 1024;
    const int t = threadIdx.x;
    const int w = t >> 6, l = t & 63;
    const int wr = (w >> 1) * 64, wc = (w & 1) * 64;
    const int lr = l & 15, lq = l >> 4;

    const floatx4 zero4 = {0.f, 0.f, 0.f, 0.f};
    floatx4 acc[4][4];
#pragma unroll
    for (int mt = 0; mt < 4; ++mt)
#pragma unroll
        for (int nt = 0; nt < 4; ++nt) acc[mt][nt] = zero4;

    for (int k0 = 0; k0 < Kd; k0 += 32) {
#pragma unroll
        for (int i = 0; i < 2; ++i) {
            int flat = t + i * 256;
            int row = flat >> 2, ch = flat & 3;
            gload_lds16(A + (size_t)(m0 + row) * Kd + k0 + ch * 8, lA + flat * 8);
            gload_lds16(B + (size_t)(n0 + row) * Kd + k0 + ch * 8, lB + flat * 8);
        }
        __syncthreads();
        short8 af[4], bfr[4];
#pragma unroll
        for (int mt = 0; mt < 4; ++mt)
            af[mt] = load8(lA + (wr + mt * 16 + lr) * 32 + lq * 8);
#pragma unroll
        for (int nt = 0; nt < 4; ++nt)
            bfr[nt] = load8(lB + (wc + nt * 16 + lr) * 32 + lq * 8);
#pragma unroll
        for (int mt = 0; mt < 4; ++mt)
#pragma unroll
            for (int nt = 0; nt < 4; ++nt)
                acc[mt][nt] = __builtin_amdgcn_mfma_f32_16x16x32_bf16(
                    af[mt], bfr[nt], acc[mt][nt], 0, 0, 0);
        __syncthreads();
    }

    if (z < 2) {
        // fused per-head L2 norm: head = 64 cols = one wave's n-band; the 16
        // lr-lanes x 4 nt-regs of a lq-quad cover the full head -> 4 shuffles.
        const float fac = (z == 0) ? (*scale_p * 1.44269504f) : 1.0f;
#pragma unroll
        for (int mt = 0; mt < 4; ++mt)
#pragma unroll
            for (int r = 0; r < 4; ++r) {
                float ss = 0.f;
#pragma unroll
                for (int nt = 0; nt < 4; ++nt) {
                    float v = acc[mt][nt][r];
                    ss += v * v;
                }
                ss += __shfl_xor(ss, 1, 64);
                ss += __shfl_xor(ss, 2, 64);
                ss += __shfl_xor(ss, 4, 64);
                ss += __shfl_xor(ss, 8, 64);
                float inv = fac / (sqrtf(ss) + 1e-6f);
#pragma unroll
                for (int nt = 0; nt < 4; ++nt) acc[mt][nt][r] *= inv;
            }
        __hip_bfloat16* C = (z == 0) ? Qb : Kb;
#pragma unroll
        for (int mt = 0; mt < 4; ++mt)
#pragma unroll
            for (int nt = 0; nt < 4; ++nt)
#pragma unroll
                for (int r = 0; r < 4; ++r) {
                    int row = m0 + wr + mt * 16 + lq * 4 + r;
                    int col = n0 + wc + nt * 16 + lr;
                    C[(size_t)row * 1024 + col] = __float2bfloat16(acc[mt][nt][r]);
                }
    } else {
        // C[e][bs] = V[bs][e] -> Vt[b][e][s], addr = b*2097152 + e*2048 + s.
        // cols are lr-contiguous in s (no 2048-boundary crossing: wc-bands are
        // 64-aligned) -> 32B-coalesced runs per 16 lanes.
#pragma unroll
        for (int mt = 0; mt < 4; ++mt)
#pragma unroll
            for (int nt = 0; nt < 4; ++nt)
#pragma unroll
                for (int r = 0; r < 4; ++r) {
                    int e = m0 + wr + mt * 16 + lq * 4 + r;
                    int col = n0 + wc + nt * 16 + lr;
                    int bb = col >> 11, s = col & 2047;
                    Vt[(size_t)bb * 2097152 + (size_t)e * 2048 + s] =
                        __float2bfloat16(acc[mt][nt][r]);
                }
    }
}

// ---------------- GEMM: C[M,N] = A[M,K] * B^T  (out-projection, fp32 out) --------
template <typename OutT>
__global__ __launch_bounds__(256) void gemm_bt(const __hip_bfloat16* __restrict__ A,
                                               const __hip_bfloat16* __restrict__ B,
                                               OutT* __restrict__ C,
                                               int N, int Kd) {
    __shared__ __hip_bfloat16 lA[128 * 32];
    __shared__ __hip_bfloat16 lB[128 * 32];
    const int t = threadIdx.x;
    const int m0 = blockIdx.x * 128, n0 = blockIdx.y * 128;
    const int w = t >> 6, l = t & 63;
    const int wr = (w >> 1) * 64, wc = (w & 1) * 64;
    const int lr = l & 15, lq = l >> 4;

    const floatx4 zero4 = {0.f, 0.f, 0.f, 0.f};
    floatx4 acc[4][4];
#pragma unroll
    for (int mt = 0; mt < 4; ++mt)
#pragma unroll
        for (int nt = 0; nt < 4; ++nt) acc[mt][nt] = zero4;

    for (int k0 = 0; k0 < Kd; k0 += 32) {
#pragma unroll
        for (int i = 0; i < 2; ++i) {
            int flat = t + i * 256;
            int row = flat >> 2, ch = flat & 3;
            gload_lds16(A + (size_t)(m0 + row) * Kd + k0 + ch * 8, lA + flat * 8);
            gload_lds16(B + (size_t)(n0 + row) * Kd + k0 + ch * 8, lB + flat * 8);
        }
        __syncthreads();
        short8 af[4], bfr[4];
#pragma unroll
        for (int mt = 0; mt < 4; ++mt)
            af[mt] = load8(lA + (wr + mt * 16 + lr) * 32 + lq * 8);
#pragma unroll
        for (int nt = 0; nt < 4; ++nt)
            bfr[nt] = load8(lB + (wc + nt * 16 + lr) * 32 + lq * 8);
#pragma unroll
        for (int mt = 0; mt < 4; ++mt)
#pragma unroll
            for (int nt = 0; nt < 4; ++nt)
                acc[mt][nt] = __builtin_amdgcn_mfma_f32_16x16x32_bf16(
                    af[mt], bfr[nt], acc[mt][nt], 0, 0, 0);
        __syncthreads();
    }
#pragma unroll
    for (int mt = 0; mt < 4; ++mt)
#pragma unroll
        for (int nt = 0; nt < 4; ++nt)
#pragma unroll
            for (int r = 0; r < 4; ++r) {
                int row = m0 + wr + mt * 16 + lq * 4 + r;
                int col = n0 + wc + nt * 16 + lr;
                storeC(C + (size_t)row * N + col, acc[mt][nt][r]);
            }
}

// ---------------- causal flash attention: LDS-staged K/V, paired q-tiles ---------
// R7 lesson: direct-from-global fragment loads hit 64 cache lines/instr -> TA-pipe
// serialization. Each wave DMAs K/V step-tiles into private LDS double buffers
// with coalesced global_load_lds, XOR-swizzled for conflict-free ds_reads.
__global__ __launch_bounds__(256, 2) void flash_attn(const __hip_bfloat16* __restrict__ Q,
                                                     const __hip_bfloat16* __restrict__ K,
                                                     const __hip_bfloat16* __restrict__ Vt,
                                                     __hip_bfloat16* __restrict__ O) {
    const int S = 2048, D = 1024;
    __shared__ __align__(16) char smem[65536];
    const int t = threadIdx.x;
    const int w = t >> 6, l = t & 63;
    const int lr = l & 15, lq = l >> 4;
    const int id = blockIdx.x;
    const int bh = (id & 7) * 4 + ((id >> 3) & 3);  // 4 heads per XCD (id%8 ~ XCD)
    const int pr = id >> 5;                          // 0..15 pair index
    const int b = bh >> 4, h = bh & 15;
    const __hip_bfloat16* Qb = Q + ((size_t)b * S) * D + h * 64;
    const __hip_bfloat16* Kb = K + ((size_t)b * S) * D + h * 64;
    const __hip_bfloat16* Vb = Vt + (size_t)bh * 64 * S;
    __hip_bfloat16* wbase = reinterpret_cast<__hip_bfloat16*>(smem) + w * 8192;
    float* buf = reinterpret_cast<float*>(smem);

    // DMA lane roles. K tile: 32 rows x 8 segs(16B); LDS[r][s] = Gl[r][s^(r&7)].
    // V tile: 64 rows x 4 segs(16B);                 LDS[r][s] = Gl[r][s^(r&3)].
    const int kr = l >> 3, ksg = (l & 7) ^ (kr & 7);
    const int vr = l >> 2, vsg = (l & 3) ^ (vr & 3);

#pragma unroll 1
    for (int tile = 0; tile < 2; ++tile) {
        const int jq = (tile == 0) ? (31 - pr) : pr;
        const int q0 = jq * 64;

        short8 bq[4][2];
#pragma unroll
        for (int nt = 0; nt < 4; ++nt)
#pragma unroll
            for (int kt = 0; kt < 2; ++kt)
                bq[nt][kt] = load8(Qb + (size_t)(q0 + nt * 16 + lr) * D + kt * 32 + lq * 8);

        const floatx4 zero4 = {0.f, 0.f, 0.f, 0.f};
        floatx4 oacc[4][4];
        float lsum[4] = {0.f, 0.f, 0.f, 0.f};
#pragma unroll
        for (int mt = 0; mt < 4; ++mt)
#pragma unroll
            for (int nt = 0; nt < 4; ++nt) oacc[mt][nt] = zero4;

        const int klast = 2 * jq + 1;
        const int kmask = 2 * jq;

        if (w <= klast) {
            {
                const int k0 = w * 32;
#pragma unroll
                for (int i = 0; i < 4; ++i)
                    gload_lds16(Kb + (size_t)(k0 + i * 8 + kr) * D + ksg * 8,
                                wbase + i * 512 + l * 8);
#pragma unroll
                for (int i = 0; i < 4; ++i)
                    gload_lds16(Vb + (size_t)(i * 16 + vr) * S + k0 + vsg * 8,
                                wbase + 4096 + i * 512 + l * 8);
            }
            int p = 0;
#pragma unroll 1
            for (int ks = w; ks <= klast; ks += 4) {
                const int k0 = ks * 32;
                asm volatile("s_waitcnt vmcnt(0)" ::: "memory");
                const __hip_bfloat16* kb = wbase + p * 2048;
                const __hip_bfloat16* vb = wbase + 4096 + p * 2048;
                short8 bk[2][2];
#pragma unroll
                for (int mt = 0; mt < 2; ++mt)
#pragma unroll
                    for (int kt = 0; kt < 2; ++kt) {
                        const int rl = mt * 16 + lr;
                        const int sg = (kt * 4 + lq) ^ (rl & 7);
                        bk[mt][kt] = load8(kb + rl * 64 + sg * 8);
                    }
                short4v bv[2][4];
#pragma unroll
                for (int mt = 0; mt < 2; ++mt)
#pragma unroll
                    for (int ntd = 0; ntd < 4; ++ntd) {
                        const int rl = ntd * 16 + lr;
                        const int sg = (mt * 2 + (lq >> 1)) ^ (rl & 3);
                        bv[mt][ntd] = load4(vb + rl * 32 + sg * 8 + (lq & 1) * 4);
                    }
                if (ks + 4 <= klast) {
                    const int kn = (ks + 4) * 32;
                    __hip_bfloat16* nb = wbase + (p ^ 1) * 2048;
#pragma unroll
                    for (int i = 0; i < 4; ++i)
                        gload_lds16(Kb + (size_t)(kn + i * 8 + kr) * D + ksg * 8,
                                    nb + i * 512 + l * 8);
#pragma unroll
                    for (int i = 0; i < 4; ++i)
                        gload_lds16(Vb + (size_t)(i * 16 + vr) * S + kn + vsg * 8,
                                    nb + 4096 + i * 512 + l * 8);
                }
                // S^T = K.Q^T
                floatx4 sacc[2][4];
#pragma unroll
                for (int mt = 0; mt < 2; ++mt)
#pragma unroll
                    for (int nt = 0; nt < 4; ++nt) sacc[mt][nt] = zero4;
#pragma unroll
                for (int mt = 0; mt < 2; ++mt)
#pragma unroll
                    for (int nt = 0; nt < 4; ++nt)
#pragma unroll
                        for (int kt = 0; kt < 2; ++kt)
                            sacc[mt][nt] = __builtin_amdgcn_mfma_f32_16x16x32_bf16(
                                bk[mt][kt], bq[nt][kt], sacc[mt][nt], 0, 0, 0);
                const bool domask = ks >= kmask;  // wave-uniform
                short4v ap[2][4];
#pragma unroll
                for (int mt = 0; mt < 2; ++mt)
#pragma unroll
                    for (int nt = 0; nt < 4; ++nt) {
                        float p0 = exp2_fast(sacc[mt][nt][0]);
                        float p1 = exp2_fast(sacc[mt][nt][1]);
                        float p2 = exp2_fast(sacc[mt][nt][2]);
                        float p3 = exp2_fast(sacc[mt][nt][3]);
                        if (domask) {
                            const int qg = q0 + nt * 16 + lr;
                            const int kb2 = k0 + mt * 16 + lq * 4;
                            p0 = (kb2 + 0 <= qg) ? p0 : 0.f;
                            p1 = (kb2 + 1 <= qg) ? p1 : 0.f;
                            p2 = (kb2 + 2 <= qg) ? p2 : 0.f;
                            p3 = (kb2 + 3 <= qg) ? p3 : 0.f;
                        }
                        lsum[nt] += (p0 + p1) + (p2 + p3);
                        S4U u;
                        u.u.x = pack_bf16(p0, p1);
                        u.u.y = pack_bf16(p2, p3);
                        ap[mt][nt] = u.v;
                    }
#pragma unroll
                for (int mt = 0; mt < 2; ++mt)
#pragma unroll
                    for (int ntq = 0; ntq < 4; ++ntq)
#pragma unroll
                        for (int ntd = 0; ntd < 4; ++ntd)
                            oacc[ntq][ntd] = mfma16(ap[mt][ntq], bv[mt][ntd], oacc[ntq][ntd]);
                p ^= 1;
            }
        }

#pragma unroll
        for (int nt = 0; nt < 4; ++nt) {
            float s = lsum[nt];
            s += __shfl_xor(s, 16, 64);
            s += __shfl_xor(s, 32, 64);
            lsum[nt] = s;
        }

        // ---- cross-wave reduce: d in 4 chunks of 16, buf[w][64][20] fp32 ----
        // FULLY UNROLLED: dynamic oacc indexing spills the accumulator to
        // scratch (R5/R6 lesson: 139 MB scratch writes from `unroll 1`).
        const int row = t >> 2, c0 = (t & 3) * 4;
        __hip_bfloat16* Ob = O + ((size_t)b * S) * D + h * 64;
        float inv = 0.f;
        __syncthreads();
#pragma unroll
        for (int chunk = 0; chunk < 4; ++chunk) {
#pragma unroll
            for (int mtq = 0; mtq < 4; ++mtq)
#pragma unroll
                for (int r = 0; r < 4; ++r)
                    buf[w * 1280 + (mtq * 16 + lq * 4 + r) * 20 + lr] = oacc[mtq][chunk][r];
            if (chunk == 0 && lq == 0) {
#pragma unroll
                for (int nt = 0; nt < 4; ++nt)
                    buf[w * 1280 + (nt * 16 + lr) * 20 + 16] = lsum[nt];
            }
            __syncthreads();
            if (chunk == 0) {
                float Lt = buf[row * 20 + 16] + buf[1280 + row * 20 + 16] +
                           buf[2560 + row * 20 + 16] + buf[3840 + row * 20 + 16];
                inv = 1.f / Lt;
            }
            float4 a = {0.f, 0.f, 0.f, 0.f};
#pragma unroll
            for (int w2 = 0; w2 < 4; ++w2) {
                float4 v = *reinterpret_cast<const float4*>(buf + w2 * 1280 + row * 20 + c0);
                a.x += v.x; a.y += v.y; a.z += v.z; a.w += v.w;
            }
            uint2 d;
            d.x = pack_bf16(a.x * inv, a.y * inv);
            d.y = pack_bf16(a.z * inv, a.w * inv);
            *reinterpret_cast<uint2*>(Ob + (size_t)(q0 + row) * D + chunk * 16 + c0) = d;
            if (chunk < 3) __syncthreads();
        }
    }
}

extern "C" void kernel_launch(void* const* d_in, const int* in_sizes, int n_in,
                              void* d_out, int out_size, void* d_ws, size_t ws_size,
                              hipStream_t stream) {
    const float* hs  = (const float*)d_in[0];  // [2,2048,1024]
    const float* wq  = (const float*)d_in[1];  // [1024,1024]
    const float* wk  = (const float*)d_in[2];
    const float* wv  = (const float*)d_in[3];
    const float* wo  = (const float*)d_in[4];
    const float* qkf = (const float*)d_in[5];  // scalar

    char* ws = (char*)d_ws;
    const size_t MB = 1024 * 1024;
    __hip_bfloat16* Xb  = (__hip_bfloat16*)(ws);            // 8 MB  [4096,1024]
    __hip_bfloat16* Wqb = (__hip_bfloat16*)(ws + 8 * MB);   // 2 MB each: Wq,Wk,Wv,Wo
    __hip_bfloat16* Wob = (__hip_bfloat16*)(ws + 14 * MB);
    __hip_bfloat16* Qb  = (__hip_bfloat16*)(ws + 16 * MB);  // 8 MB [4096,1024]
    __hip_bfloat16* Kb  = (__hip_bfloat16*)(ws + 24 * MB);  // 8 MB [4096,1024]
    __hip_bfloat16* Vt  = (__hip_bfloat16*)(ws + 40 * MB);  // 8 MB [B,1024,2048]
    __hip_bfloat16* Ab  = (__hip_bfloat16*)(ws + 48 * MB);  // 8 MB attn out

    cast_all<<<dim3(4096, 2), 256, 0, stream>>>(hs, wq, wk, wv, wo, Xb, Wqb);

    // Q,K (fused hypersphere norm; Q scaled by qkf*log2e) + V stored transposed
    gemm_qkv<<<dim3(32, 8, 3), 256, 0, stream>>>(Xb, Wqb, Qb, Kb, Vt, qkf);

    flash_attn<<<512, 256, 0, stream>>>(Qb, Kb, Vt, Ab);

    gemm_bt<float><<<dim3(32, 8), 256, 0, stream>>>(Ab, Wob, (float*)d_out, 1024, 1024);
}